// Round 8
// baseline (1600.164 us; speedup 1.0000x reference)
//
#include <hip/hip_runtime.h>
#include <hip/hip_bf16.h>

#define NN 50000
#define EE 800000
#define HD 64
#define LL 14
#define IND 128
#define OUTD 112
#define LN2 0.69314718056f

typedef __attribute__((ext_vector_type(8))) short short8;
typedef __attribute__((ext_vector_type(4))) float float4_;
typedef __attribute__((ext_vector_type(4))) unsigned short ushort4_;

__device__ __forceinline__ short bf16_hi(float x) {
    return (short)(__float_as_uint(x) >> 16);  // truncation split
}
__device__ __forceinline__ float bf16_f(short s) {
    return __uint_as_float(((unsigned)(unsigned short)s) << 16);
}
__device__ __forceinline__ float us2f(unsigned u) {
    return __uint_as_float(u << 16);
}
// round-to-nearest-even fp32 -> bf16 bits
__device__ __forceinline__ unsigned short f2b_rne(float x) {
    unsigned u = __float_as_uint(x);
    u += 0x7fffu + ((u >> 16) & 1u);
    return (unsigned short)(u >> 16);
}

// split 8 consecutive fp32 (16B-aligned) into bf16 hi/lo fragments
__device__ __forceinline__ void split8(const float* p, short8& hi, short8& lo) {
    float4_ a = *(const float4_*)p;
    float4_ b = *(const float4_*)(p + 4);
    float v[8] = {a[0], a[1], a[2], a[3], b[0], b[1], b[2], b[3]};
    #pragma unroll
    for (int j = 0; j < 8; ++j) {
        short h = bf16_hi(v[j]);
        hi[j] = h;
        lo[j] = bf16_hi(v[j] - bf16_f(h));
    }
}

// load B-fragment (8 k-rows of one 16-col slice) from global weights, hi/lo split
__device__ __forceinline__ void load_b(const float* __restrict__ W, int ldw,
                                       int colbase, int krow, short8& hi, short8& lo) {
    #pragma unroll
    for (int j = 0; j < 8; ++j) {
        float wv = W[(krow + j) * ldw + colbase];
        short h = bf16_hi(wv);
        hi[j] = h;
        lo[j] = bf16_hi(wv - bf16_f(h));
    }
}

// fp32-accurate product via 3 bf16 MFMAs (drop lo*lo)
__device__ __forceinline__ float4_ mm3(short8 ah, short8 al, short8 bh, short8 bl,
                                       float4_ acc) {
    acc = __builtin_amdgcn_mfma_f32_16x16x32_bf16(ah, bh, acc, 0, 0, 0);
    acc = __builtin_amdgcn_mfma_f32_16x16x32_bf16(al, bh, acc, 0, 0, 0);
    acc = __builtin_amdgcn_mfma_f32_16x16x32_bf16(ah, bl, acc, 0, 0, 0);
    return acc;
}

// ---------------- CSR build ----------------

__global__ void k_hist(const int* __restrict__ ei, int* __restrict__ cnt,
                       int* __restrict__ rank) {
    int e = blockIdx.x * blockDim.x + threadIdx.x;
    if (e < EE) rank[e] = atomicAdd(&cnt[ei[EE + e]], 1);
}

__global__ __launch_bounds__(1024) void k_scan1(const int* __restrict__ deg,
                                                int* __restrict__ excl,
                                                int* __restrict__ bsum) {
    __shared__ int ws[16];
    int tid = threadIdx.x, lane = tid & 63, w = tid >> 6;
    int gid = blockIdx.x * 1024 + tid;
    int v = (gid < NN) ? deg[gid] : 0;
    int x = v;
    #pragma unroll
    for (int d = 1; d < 64; d <<= 1) {
        int y = __shfl_up(x, d);
        if (lane >= d) x += y;
    }
    if (lane == 63) ws[w] = x;
    __syncthreads();
    if (tid == 0) {
        int acc = 0;
        for (int i = 0; i < 16; i++) { int t = ws[i]; ws[i] = acc; acc += t; }
        bsum[blockIdx.x] = acc;
    }
    __syncthreads();
    if (gid < NN) excl[gid] = x - v + ws[w];
}

// one-wave shuffle scan (nb <= 64)
__global__ void k_scan2(const int* __restrict__ bsum, int* __restrict__ boff, int nb) {
    int lane = threadIdx.x & 63;
    int v = (lane < nb) ? bsum[lane] : 0;
    int x = v;
    #pragma unroll
    for (int d = 1; d < 64; d <<= 1) {
        int y = __shfl_up(x, d);
        if (lane >= d) x += y;
    }
    if (lane < nb) boff[lane] = x - v;
}

__global__ __launch_bounds__(1024) void k_scan3(int* __restrict__ rp,
                                                const int* __restrict__ boff) {
    int gid = blockIdx.x * 1024 + threadIdx.x;
    if (gid < NN) rp[gid] += boff[blockIdx.x];
    if (gid == 0) rp[NN] = EE;
}

__global__ void k_scatter(const int* __restrict__ ei, const int* __restrict__ rp,
                          const int* __restrict__ rank, int* __restrict__ csrc) {
    int e = blockIdx.x * blockDim.x + threadIdx.x;
    if (e < EE) {
        int d = ei[EE + e];
        csrc[rp[d] + rank[e]] = ei[e];
    }
}

// ---------------- Encoder: h0 = x @ enc_W + enc_b, plus slice-major P0 ----------------
// P layout: P[slice][node][8ch], slice = ch/8. 800KB per slice.

__global__ __launch_bounds__(256) void k_enc(const float* __restrict__ x,
                                             const float* __restrict__ W,
                                             const float* __restrict__ b,
                                             float* __restrict__ h,
                                             unsigned short* __restrict__ P0) {
    __shared__ float X[16 * 132];
    int tid = threadIdx.x, lane = tid & 63, w = tid >> 6;
    int nb = blockIdx.x * 16;
    int nq = lane >> 4, nr = lane & 15;
    int colbase = w * 16 + nr;

    {
        const float* src = x + (size_t)nb * IND + tid * 8;
        float4_ a = *(const float4_*)src;
        float4_ c = *(const float4_*)(src + 4);
        int m = tid >> 4, k8 = 8 * (tid & 15);
        *(float4_*)&X[m * 132 + k8] = a;
        *(float4_*)&X[m * 132 + k8 + 4] = c;
    }
    __syncthreads();

    float4_ acc = {};
    #pragma unroll
    for (int t = 0; t < 4; ++t) {
        short8 ah, al, bh, bl;
        split8(&X[nr * 132 + t * 32 + nq * 8], ah, al);
        load_b(W, HD, colbase, t * 32 + nq * 8, bh, bl);
        acc = mm3(ah, al, bh, bl, acc);
    }

    float bias = b[colbase];
    size_t sbase = ((size_t)(colbase >> 3)) * NN;
    int off = colbase & 7;
    #pragma unroll
    for (int r = 0; r < 4; ++r) {
        int node = nb + nq * 4 + r;
        float y = acc[r] + bias;
        h[node * HD + colbase] = y;
        float msg = fminf(fmaxf(y, 0.f) + 1e-7f, 50.f);
        P0[(sbase + node) * 8 + off] = f2b_rne(__expf(msg));
    }
}

// ---------------- Gather: XCD-sliced channels, conservative R5-shaped kernel ----------
// slice = blockIdx.x & 7 (round-robin -> one XCD per slice); each XCD touches only
// its 800KB P-slice -> L2-resident. 256 threads = 4 waves; wave = 2 nodes x 1 slice.
// Lane = (es = edge-slot 0..7) x (ch = channel 0..7).

__global__ __launch_bounds__(256) void k_gather(const unsigned short* __restrict__ Pin,
                                                const float* __restrict__ selfh,  // layer0 only
                                                float* __restrict__ gT,
                                                const int* __restrict__ rp,
                                                const int* __restrict__ csrc) {
    int w = threadIdx.x >> 6, lane = threadIdx.x & 63;
    int slice = blockIdx.x & 7;
    int nb = (blockIdx.x >> 3) * 8 + w * 2;     // grid = (NN/8)*8 exactly
    int es = lane >> 3, ch = lane & 7;
    const unsigned short* Ps = Pin + (size_t)slice * NN * 8;

    for (int i = 0; i < 2; ++i) {
        int node = nb + i;                       // always < NN (NN % 8 == 0)
        int beg = rp[node];
        int deg = rp[node + 1] - beg;

        float s = 0.f, n = 0.f;
        int waste = 0;
        for (int chunk = 0; chunk < deg; chunk += 64) {
            int cnt = min(64, deg - chunk);
            int my = (lane < cnt) ? csrc[beg + chunk + lane] : 0;
            int rounds = (cnt + 7) >> 3;
            waste += rounds * 8 - cnt;
            for (int r = 0; r < rounds; ++r) {
                int idx = r * 8 + es;
                int src = __shfl(my, idx);
                float p = (idx < cnt) ? us2f(Ps[src * 8 + ch]) : 1.0f;
                n = fmaf(p, __log2f(p), n);      // log2(1)=0 for padded slots
                s += p;
            }
        }
        // reduce over the 8 edge-slot lanes (bits 3..5)
        #pragma unroll
        for (int d = 8; d < 64; d <<= 1) {
            s += __shfl_xor(s, d);
            n += __shfl_xor(n, d);
        }
        if (es == 0) {
            float agg = LN2 * n / fmaxf(s - (float)waste, 1e-16f);
            float self;
            if (selfh) self = selfh[(size_t)node * HD + slice * 8 + ch];
            else       self = LN2 * __log2f(us2f(Ps[(size_t)node * 8 + ch])) - 1e-7f;
            gT[(size_t)node * HD + slice * 8 + ch] = self + agg;
        }
    }
}

// ---------------- Dense layer: hout = gT @ W + b (+hres); LN -> slice-major Pout ----------------

__global__ __launch_bounds__(256) void k_mm(const float* __restrict__ gT,
                                            const float* __restrict__ hres,
                                            float* __restrict__ hout,
                                            unsigned short* __restrict__ Pout,
                                            const float* __restrict__ W,
                                            const float* __restrict__ b,
                                            const float* __restrict__ gnext,
                                            const float* __restrict__ bnext) {
    __shared__ float T[16 * 68];
    int tid = threadIdx.x, lane = tid & 63, w = tid >> 6;
    int nb = blockIdx.x * 16;
    int nq = lane >> 4, nr = lane & 15;
    int colbase = w * 16 + nr;

    {
        const float* src = gT + (size_t)nb * HD + tid * 4;
        float4_ a = *(const float4_*)src;
        int m = tid >> 4, k4 = 4 * (tid & 15);
        *(float4_*)&T[m * 68 + k4] = a;
    }
    __syncthreads();

    short8 Ahi[2], Alo[2];
    #pragma unroll
    for (int t = 0; t < 2; ++t)
        split8(&T[nr * 68 + t * 32 + nq * 8], Ahi[t], Alo[t]);
    __syncthreads();  // all A reads done before T is overwritten

    float4_ acc = {};
    #pragma unroll
    for (int t = 0; t < 2; ++t) {
        short8 bh, bl;
        load_b(W, HD, colbase, t * 32 + nq * 8, bh, bl);
        acc = mm3(Ahi[t], Alo[t], bh, bl, acc);
    }

    float bias = b[colbase];
    #pragma unroll
    for (int r = 0; r < 4; ++r) {
        int m = nq * 4 + r;
        int node = nb + m;
        float v = acc[r] + bias;
        if (hres) v += hres[node * HD + colbase];
        hout[node * HD + colbase] = v;
        T[m * 68 + colbase] = v;
    }
    if (!Pout) return;
    __syncthreads();

    // LN phase: thread -> node tid>>4, 4 channels; emit P = bf16(exp(msg)) slice-major
    int m = tid >> 4, c4 = (tid & 15) * 4;
    float4_ vv = *(const float4_*)&T[m * 68 + c4];
    float ps_ = (vv[0] + vv[1]) + (vv[2] + vv[3]);
    float pq_ = (vv[0] * vv[0] + vv[1] * vv[1]) + (vv[2] * vv[2] + vv[3] * vv[3]);
    #pragma unroll
    for (int d = 8; d; d >>= 1) {
        ps_ += __shfl_xor(ps_, d);
        pq_ += __shfl_xor(pq_, d);
    }
    float mu = ps_ * (1.f / 64.f);
    float var = pq_ * (1.f / 64.f) - mu * mu;
    float inv = rsqrtf(fmaxf(var, 0.f) + 1e-5f);
    float4_ g4 = *(const float4_*)&gnext[c4];
    float4_ b4 = *(const float4_*)&bnext[c4];
    ushort4_ po;
    #pragma unroll
    for (int j = 0; j < 4; ++j) {
        float y = fmaxf((vv[j] - mu) * inv * g4[j] + b4[j], 0.f);
        float msg = fminf(y + 1e-7f, 50.f);
        po[j] = f2b_rne(__expf(msg));
    }
    int slice = c4 >> 3, off = c4 & 7;
    *(ushort4_*)&Pout[((size_t)slice * NN + (nb + m)) * 8 + off] = po;
}

// ---------------- Predictor: out = h @ pred_W + pred_b  (MFMA) ----------------

__global__ __launch_bounds__(256) void k_pred(const float* __restrict__ h,
                                              const float* __restrict__ W,
                                              const float* __restrict__ b,
                                              float* __restrict__ out) {
    __shared__ float T[16 * 68];
    int tid = threadIdx.x, lane = tid & 63, w = tid >> 6;
    int nb = blockIdx.x * 16;
    int nq = lane >> 4, nr = lane & 15;

    {
        const float* src = h + (size_t)nb * HD + tid * 4;
        float4_ a = *(const float4_*)src;
        int m = tid >> 4, k4 = 4 * (tid & 15);
        *(float4_*)&T[m * 68 + k4] = a;
    }
    __syncthreads();

    short8 Ahi[2], Alo[2];
    #pragma unroll
    for (int t = 0; t < 2; ++t)
        split8(&T[nr * 68 + t * 32 + nq * 8], Ahi[t], Alo[t]);

    for (int tt = w; tt < 7; tt += 4) {
        int colbase = tt * 16 + nr;
        float4_ acc = {};
        #pragma unroll
        for (int t = 0; t < 2; ++t) {
            short8 bh, bl;
            load_b(W, OUTD, colbase, t * 32 + nq * 8, bh, bl);
            acc = mm3(Ahi[t], Alo[t], bh, bl, acc);
        }
        float bias = b[colbase];
        #pragma unroll
        for (int r = 0; r < 4; ++r) {
            int node = nb + nq * 4 + r;
            out[node * OUTD + colbase] = acc[r] + bias;
        }
    }
}

// ---------------- Launch ----------------

extern "C" void kernel_launch(void* const* d_in, const int* in_sizes, int n_in,
                              void* d_out, int out_size, void* d_ws, size_t ws_size,
                              hipStream_t stream) {
    const float* x    = (const float*)d_in[0];
    const int*   ei   = (const int*)d_in[1];
    const float* encW = (const float*)d_in[2];
    const float* encb = (const float*)d_in[3];
    const float* lng  = (const float*)d_in[4];
    const float* lnb  = (const float*)d_in[5];
    const float* mlpW = (const float*)d_in[6];
    const float* mlpb = (const float*)d_in[7];
    const float* pW   = (const float*)d_in[8];
    const float* pb   = (const float*)d_in[9];
    float* out = (float*)d_out;

    float* hA  = (float*)d_ws;
    float* hB  = hA + (size_t)NN * HD;
    float* gT  = hB + (size_t)NN * HD;
    unsigned short* PA = (unsigned short*)(gT + (size_t)NN * HD);
    unsigned short* PB = PA + (size_t)NN * HD;
    int* rp    = (int*)(PB + (size_t)NN * HD);
    int* cnt   = rp + (NN + 1);
    int* csrc  = cnt + NN;
    int* rank  = csrc + EE;
    int* bsum  = rank + EE;
    int* boff  = bsum + 64;

    // CSR build (per call; ws is re-poisoned each launch)
    hipMemsetAsync(cnt, 0, NN * sizeof(int), stream);
    k_hist<<<(EE + 255) / 256, 256, 0, stream>>>(ei, cnt, rank);
    const int NB = (NN + 1023) / 1024;  // 49
    k_scan1<<<NB, 1024, 0, stream>>>(cnt, rp, bsum);
    k_scan2<<<1, 64, 0, stream>>>(bsum, boff, NB);
    k_scan3<<<NB, 1024, 0, stream>>>(rp, boff);
    k_scatter<<<(EE + 255) / 256, 256, 0, stream>>>(ei, rp, rank, csrc);

    // Encoder -> h_0 in hA, slice-major P_0 in PA
    k_enc<<<NN / 16, 256, 0, stream>>>(x, encW, encb, hA, PA);

    const int GB = (NN / 8) * 8;  // 50000 blocks: (nodeblock, slice)

    // Layer 0: gather from P_0 with self = raw h0; dense -> h_1 in hB, P_1 in PB
    k_gather<<<GB, 256, 0, stream>>>(PA, hA, gT, rp, csrc);
    k_mm<<<NN / 16, 256, 0, stream>>>(gT, nullptr, hB, PB,
                                      mlpW, mlpb, lng, lnb);

    float* hres = hB;   // h_1
    float* hdst = hA;
    unsigned short* pc = PB;
    unsigned short* pn = PA;
    for (int l = 1; l < LL; ++l) {
        bool last = (l == LL - 1);
        k_gather<<<GB, 256, 0, stream>>>(pc, nullptr, gT, rp, csrc);
        k_mm<<<NN / 16, 256, 0, stream>>>(gT, hres, hdst,
                                          last ? nullptr : pn,
                                          mlpW + (size_t)l * HD * HD,
                                          mlpb + (size_t)l * HD,
                                          last ? nullptr : lng + (size_t)l * HD,
                                          last ? nullptr : lnb + (size_t)l * HD);
        float* t = hres; hres = hdst; hdst = t;
        unsigned short* u = pc; pc = pn; pn = u;
    }

    // Predictor on h_14
    k_pred<<<NN / 16, 256, 0, stream>>>(hres, pW, pb, out);
}

// Round 9
// 1120.428 us; speedup vs baseline: 1.4282x; 1.4282x over previous
//
#include <hip/hip_runtime.h>
#include <hip/hip_bf16.h>

#define NN 50000
#define EE 800000
#define HD 64
#define LL 14
#define IND 128
#define OUTD 112
#define LN2 0.69314718056f

typedef __attribute__((ext_vector_type(8))) short short8;
typedef __attribute__((ext_vector_type(4))) float float4_;
typedef __attribute__((ext_vector_type(4))) unsigned short ushort4_;

__device__ __forceinline__ short bf16_hi(float x) {
    return (short)(__float_as_uint(x) >> 16);  // truncation split
}
__device__ __forceinline__ float bf16_f(short s) {
    return __uint_as_float(((unsigned)(unsigned short)s) << 16);
}
__device__ __forceinline__ float us2f(unsigned u) {
    return __uint_as_float(u << 16);
}
// round-to-nearest-even fp32 -> bf16 bits
__device__ __forceinline__ unsigned short f2b_rne(float x) {
    unsigned u = __float_as_uint(x);
    u += 0x7fffu + ((u >> 16) & 1u);
    return (unsigned short)(u >> 16);
}

// split 8 consecutive fp32 (16B-aligned) into bf16 hi/lo fragments
__device__ __forceinline__ void split8(const float* p, short8& hi, short8& lo) {
    float4_ a = *(const float4_*)p;
    float4_ b = *(const float4_*)(p + 4);
    float v[8] = {a[0], a[1], a[2], a[3], b[0], b[1], b[2], b[3]};
    #pragma unroll
    for (int j = 0; j < 8; ++j) {
        short h = bf16_hi(v[j]);
        hi[j] = h;
        lo[j] = bf16_hi(v[j] - bf16_f(h));
    }
}

// load B-fragment (8 k-rows of one 16-col slice) from global weights, hi/lo split
__device__ __forceinline__ void load_b(const float* __restrict__ W, int ldw,
                                       int colbase, int krow, short8& hi, short8& lo) {
    #pragma unroll
    for (int j = 0; j < 8; ++j) {
        float wv = W[(krow + j) * ldw + colbase];
        short h = bf16_hi(wv);
        hi[j] = h;
        lo[j] = bf16_hi(wv - bf16_f(h));
    }
}

// fp32-accurate product via 3 bf16 MFMAs (drop lo*lo)
__device__ __forceinline__ float4_ mm3(short8 ah, short8 al, short8 bh, short8 bl,
                                       float4_ acc) {
    acc = __builtin_amdgcn_mfma_f32_16x16x32_bf16(ah, bh, acc, 0, 0, 0);
    acc = __builtin_amdgcn_mfma_f32_16x16x32_bf16(al, bh, acc, 0, 0, 0);
    acc = __builtin_amdgcn_mfma_f32_16x16x32_bf16(ah, bl, acc, 0, 0, 0);
    return acc;
}

// ---------------- CSR build ----------------

__global__ void k_hist(const int* __restrict__ ei, int* __restrict__ cnt,
                       int* __restrict__ rank) {
    int e = blockIdx.x * blockDim.x + threadIdx.x;
    if (e < EE) rank[e] = atomicAdd(&cnt[ei[EE + e]], 1);
}

__global__ __launch_bounds__(1024) void k_scan1(const int* __restrict__ deg,
                                                int* __restrict__ excl,
                                                int* __restrict__ bsum) {
    __shared__ int ws[16];
    int tid = threadIdx.x, lane = tid & 63, w = tid >> 6;
    int gid = blockIdx.x * 1024 + tid;
    int v = (gid < NN) ? deg[gid] : 0;
    int x = v;
    #pragma unroll
    for (int d = 1; d < 64; d <<= 1) {
        int y = __shfl_up(x, d);
        if (lane >= d) x += y;
    }
    if (lane == 63) ws[w] = x;
    __syncthreads();
    if (tid == 0) {
        int acc = 0;
        for (int i = 0; i < 16; i++) { int t = ws[i]; ws[i] = acc; acc += t; }
        bsum[blockIdx.x] = acc;
    }
    __syncthreads();
    if (gid < NN) excl[gid] = x - v + ws[w];
}

// one-wave shuffle scan (nb <= 64)
__global__ void k_scan2(const int* __restrict__ bsum, int* __restrict__ boff, int nb) {
    int lane = threadIdx.x & 63;
    int v = (lane < nb) ? bsum[lane] : 0;
    int x = v;
    #pragma unroll
    for (int d = 1; d < 64; d <<= 1) {
        int y = __shfl_up(x, d);
        if (lane >= d) x += y;
    }
    if (lane < nb) boff[lane] = x - v;
}

__global__ __launch_bounds__(1024) void k_scan3(int* __restrict__ rp,
                                                const int* __restrict__ boff) {
    int gid = blockIdx.x * 1024 + threadIdx.x;
    if (gid < NN) rp[gid] += boff[blockIdx.x];
    if (gid == 0) rp[NN] = EE;
}

__global__ void k_scatter(const int* __restrict__ ei, const int* __restrict__ rp,
                          const int* __restrict__ rank, int* __restrict__ csrc) {
    int e = blockIdx.x * blockDim.x + threadIdx.x;
    if (e < EE) {
        int d = ei[EE + e];
        csrc[rp[d] + rank[e]] = ei[e];
    }
}

// ---------------- Encoder: h0 = x @ enc_W + enc_b, plus half-major P0 ----------------
// P layout: P[half][node][32ch] ushort, half = ch/32. 3.2MB per half (< 4MB L2/XCD).

__global__ __launch_bounds__(256) void k_enc(const float* __restrict__ x,
                                             const float* __restrict__ W,
                                             const float* __restrict__ b,
                                             float* __restrict__ h,
                                             unsigned short* __restrict__ P0) {
    __shared__ float X[16 * 132];
    int tid = threadIdx.x, lane = tid & 63, w = tid >> 6;
    int nb = blockIdx.x * 16;
    int nq = lane >> 4, nr = lane & 15;
    int colbase = w * 16 + nr;

    {
        const float* src = x + (size_t)nb * IND + tid * 8;
        float4_ a = *(const float4_*)src;
        float4_ c = *(const float4_*)(src + 4);
        int m = tid >> 4, k8 = 8 * (tid & 15);
        *(float4_*)&X[m * 132 + k8] = a;
        *(float4_*)&X[m * 132 + k8 + 4] = c;
    }
    __syncthreads();

    float4_ acc = {};
    #pragma unroll
    for (int t = 0; t < 4; ++t) {
        short8 ah, al, bh, bl;
        split8(&X[nr * 132 + t * 32 + nq * 8], ah, al);
        load_b(W, HD, colbase, t * 32 + nq * 8, bh, bl);
        acc = mm3(ah, al, bh, bl, acc);
    }

    float bias = b[colbase];
    size_t hbase = ((size_t)(colbase >> 5)) * NN;   // half base (nodes)
    int off = colbase & 31;
    #pragma unroll
    for (int r = 0; r < 4; ++r) {
        int node = nb + nq * 4 + r;
        float y = acc[r] + bias;
        h[node * HD + colbase] = y;
        float msg = fminf(fmaxf(y, 0.f) + 1e-7f, 50.f);
        P0[(hbase + node) * 32 + off] = f2b_rne(__expf(msg));
    }
}

// ---------------- Gather: 32-channel halves, L2-resident per XCD ----------------
// half = blockIdx.x & 1 (round-robin XCD dispatch keeps each XCD on one 3.2MB
// half-slice -> L2-resident). Block = 4 waves; wave = 1 node; lane = 2 edge-slots
// x 32 ch. One 64B coalesced segment per edge-slot per step.

__global__ __launch_bounds__(256) void k_gather(const unsigned short* __restrict__ Pin,
                                                const float* __restrict__ selfh,  // layer0 only
                                                float* __restrict__ gT,
                                                const int* __restrict__ rp,
                                                const int* __restrict__ csrc) {
    int w = threadIdx.x >> 6, lane = threadIdx.x & 63;
    int half = blockIdx.x & 1;
    int node = (blockIdx.x >> 1) * 4 + w;        // grid = (NN/4)*2, node < NN always
    int es = lane >> 5, ch = lane & 31;
    const unsigned short* Ps = Pin + (size_t)half * NN * 32;

    int beg = rp[node];
    int deg = rp[node + 1] - beg;

    float s = 0.f, n = 0.f;
    int waste = 0;
    for (int chunk = 0; chunk < deg; chunk += 64) {
        int cnt = min(64, deg - chunk);
        int my = (lane < cnt) ? csrc[beg + chunk + lane] : 0;
        waste += cnt & 1;                         // odd tail: one padded slot
        for (int e = 0; e < cnt; e += 2) {
            int s0 = __shfl(my, e);
            int s1 = __shfl(my, e + 1);          // index <= 63; my[cnt]=0 if odd
            int src = es ? s1 : s0;
            float p = ((e + es) < cnt) ? us2f(Ps[src * 32 + ch]) : 1.0f;
            n = fmaf(p, __log2f(p), n);          // log2(1)=0 for padded slot
            s += p;
        }
    }
    // reduce over the 2 edge-slot groups (bit 5)
    s += __shfl_xor(s, 32);
    n += __shfl_xor(n, 32);

    if (lane < 32) {                              // es==0 lanes, ch = lane
        float agg = LN2 * n / fmaxf(s - (float)waste, 1e-16f);
        float self;
        if (selfh) self = selfh[(size_t)node * HD + half * 32 + ch];
        else       self = LN2 * __log2f(us2f(Ps[(size_t)node * 32 + ch])) - 1e-7f;
        gT[(size_t)node * HD + half * 32 + ch] = self + agg;
    }
}

// ---------------- Dense layer: hout = gT @ W + b (+hres); LN -> half-major Pout ----------------

__global__ __launch_bounds__(256) void k_mm(const float* __restrict__ gT,
                                            const float* __restrict__ hres,
                                            float* __restrict__ hout,
                                            unsigned short* __restrict__ Pout,
                                            const float* __restrict__ W,
                                            const float* __restrict__ b,
                                            const float* __restrict__ gnext,
                                            const float* __restrict__ bnext) {
    __shared__ float T[16 * 68];
    int tid = threadIdx.x, lane = tid & 63, w = tid >> 6;
    int nb = blockIdx.x * 16;
    int nq = lane >> 4, nr = lane & 15;
    int colbase = w * 16 + nr;

    {
        const float* src = gT + (size_t)nb * HD + tid * 4;
        float4_ a = *(const float4_*)src;
        int m = tid >> 4, k4 = 4 * (tid & 15);
        *(float4_*)&T[m * 68 + k4] = a;
    }
    __syncthreads();

    short8 Ahi[2], Alo[2];
    #pragma unroll
    for (int t = 0; t < 2; ++t)
        split8(&T[nr * 68 + t * 32 + nq * 8], Ahi[t], Alo[t]);
    __syncthreads();  // all A reads done before T is overwritten

    float4_ acc = {};
    #pragma unroll
    for (int t = 0; t < 2; ++t) {
        short8 bh, bl;
        load_b(W, HD, colbase, t * 32 + nq * 8, bh, bl);
        acc = mm3(Ahi[t], Alo[t], bh, bl, acc);
    }

    float bias = b[colbase];
    #pragma unroll
    for (int r = 0; r < 4; ++r) {
        int m = nq * 4 + r;
        int node = nb + m;
        float v = acc[r] + bias;
        if (hres) v += hres[node * HD + colbase];
        hout[node * HD + colbase] = v;
        T[m * 68 + colbase] = v;
    }
    if (!Pout) return;
    __syncthreads();

    // LN phase: thread -> node tid>>4, 4 channels; emit P = bf16(exp(msg)) half-major
    int m = tid >> 4, c4 = (tid & 15) * 4;
    float4_ vv = *(const float4_*)&T[m * 68 + c4];
    float ps_ = (vv[0] + vv[1]) + (vv[2] + vv[3]);
    float pq_ = (vv[0] * vv[0] + vv[1] * vv[1]) + (vv[2] * vv[2] + vv[3] * vv[3]);
    #pragma unroll
    for (int d = 8; d; d >>= 1) {
        ps_ += __shfl_xor(ps_, d);
        pq_ += __shfl_xor(pq_, d);
    }
    float mu = ps_ * (1.f / 64.f);
    float var = pq_ * (1.f / 64.f) - mu * mu;
    float inv = rsqrtf(fmaxf(var, 0.f) + 1e-5f);
    float4_ g4 = *(const float4_*)&gnext[c4];
    float4_ b4 = *(const float4_*)&bnext[c4];
    ushort4_ po;
    #pragma unroll
    for (int j = 0; j < 4; ++j) {
        float y = fmaxf((vv[j] - mu) * inv * g4[j] + b4[j], 0.f);
        float msg = fminf(y + 1e-7f, 50.f);
        po[j] = f2b_rne(__expf(msg));
    }
    int half = c4 >> 5, off = c4 & 31;
    *(ushort4_*)&Pout[((size_t)half * NN + (nb + m)) * 32 + off] = po;
}

// ---------------- Predictor: out = h @ pred_W + pred_b  (MFMA) ----------------

__global__ __launch_bounds__(256) void k_pred(const float* __restrict__ h,
                                              const float* __restrict__ W,
                                              const float* __restrict__ b,
                                              float* __restrict__ out) {
    __shared__ float T[16 * 68];
    int tid = threadIdx.x, lane = tid & 63, w = tid >> 6;
    int nb = blockIdx.x * 16;
    int nq = lane >> 4, nr = lane & 15;

    {
        const float* src = h + (size_t)nb * HD + tid * 4;
        float4_ a = *(const float4_*)src;
        int m = tid >> 4, k4 = 4 * (tid & 15);
        *(float4_*)&T[m * 68 + k4] = a;
    }
    __syncthreads();

    short8 Ahi[2], Alo[2];
    #pragma unroll
    for (int t = 0; t < 2; ++t)
        split8(&T[nr * 68 + t * 32 + nq * 8], Ahi[t], Alo[t]);

    for (int tt = w; tt < 7; tt += 4) {
        int colbase = tt * 16 + nr;
        float4_ acc = {};
        #pragma unroll
        for (int t = 0; t < 2; ++t) {
            short8 bh, bl;
            load_b(W, OUTD, colbase, t * 32 + nq * 8, bh, bl);
            acc = mm3(Ahi[t], Alo[t], bh, bl, acc);
        }
        float bias = b[colbase];
        #pragma unroll
        for (int r = 0; r < 4; ++r) {
            int node = nb + nq * 4 + r;
            out[node * OUTD + colbase] = acc[r] + bias;
        }
    }
}

// ---------------- Launch ----------------

extern "C" void kernel_launch(void* const* d_in, const int* in_sizes, int n_in,
                              void* d_out, int out_size, void* d_ws, size_t ws_size,
                              hipStream_t stream) {
    const float* x    = (const float*)d_in[0];
    const int*   ei   = (const int*)d_in[1];
    const float* encW = (const float*)d_in[2];
    const float* encb = (const float*)d_in[3];
    const float* lng  = (const float*)d_in[4];
    const float* lnb  = (const float*)d_in[5];
    const float* mlpW = (const float*)d_in[6];
    const float* mlpb = (const float*)d_in[7];
    const float* pW   = (const float*)d_in[8];
    const float* pb   = (const float*)d_in[9];
    float* out = (float*)d_out;

    float* hA  = (float*)d_ws;
    float* hB  = hA + (size_t)NN * HD;
    float* gT  = hB + (size_t)NN * HD;
    unsigned short* PA = (unsigned short*)(gT + (size_t)NN * HD);
    unsigned short* PB = PA + (size_t)NN * HD;
    int* rp    = (int*)(PB + (size_t)NN * HD);
    int* cnt   = rp + (NN + 1);
    int* csrc  = cnt + NN;
    int* rank  = csrc + EE;
    int* bsum  = rank + EE;
    int* boff  = bsum + 64;

    // CSR build (per call; ws is re-poisoned each launch)
    hipMemsetAsync(cnt, 0, NN * sizeof(int), stream);
    k_hist<<<(EE + 255) / 256, 256, 0, stream>>>(ei, cnt, rank);
    const int NB = (NN + 1023) / 1024;  // 49
    k_scan1<<<NB, 1024, 0, stream>>>(cnt, rp, bsum);
    k_scan2<<<1, 64, 0, stream>>>(bsum, boff, NB);
    k_scan3<<<NB, 1024, 0, stream>>>(rp, boff);
    k_scatter<<<(EE + 255) / 256, 256, 0, stream>>>(ei, rp, rank, csrc);

    // Encoder -> h_0 in hA, half-major P_0 in PA
    k_enc<<<NN / 16, 256, 0, stream>>>(x, encW, encb, hA, PA);

    const int GB = (NN / 4) * 2;  // 25000 blocks: (nodegroup, half)

    // Layer 0: gather from P_0 with self = raw h0; dense -> h_1 in hB, P_1 in PB
    k_gather<<<GB, 256, 0, stream>>>(PA, hA, gT, rp, csrc);
    k_mm<<<NN / 16, 256, 0, stream>>>(gT, nullptr, hB, PB,
                                      mlpW, mlpb, lng, lnb);

    float* hres = hB;   // h_1
    float* hdst = hA;
    unsigned short* pc = PB;
    unsigned short* pn = PA;
    for (int l = 1; l < LL; ++l) {
        bool last = (l == LL - 1);
        k_gather<<<GB, 256, 0, stream>>>(pc, nullptr, gT, rp, csrc);
        k_mm<<<NN / 16, 256, 0, stream>>>(gT, hres, hdst,
                                          last ? nullptr : pn,
                                          mlpW + (size_t)l * HD * HD,
                                          mlpb + (size_t)l * HD,
                                          last ? nullptr : lng + (size_t)l * HD,
                                          last ? nullptr : lnb + (size_t)l * HD);
        float* t = hres; hres = hdst; hdst = t;
        unsigned short* u = pc; pc = pn; pn = u;
    }

    // Predictor on h_14
    k_pred<<<NN / 16, 256, 0, stream>>>(hres, pW, pb, out);
}

// Round 10
// 646.849 us; speedup vs baseline: 2.4738x; 1.7321x over previous
//
#include <hip/hip_runtime.h>
#include <hip/hip_bf16.h>

#define NN 50000
#define EE 800000
#define HD 64
#define LL 14
#define IND 128
#define OUTD 112
#define LN2 0.69314718056f

typedef __attribute__((ext_vector_type(8))) short short8;
typedef __attribute__((ext_vector_type(4))) float float4_;
typedef __attribute__((ext_vector_type(4))) unsigned short ushort4_;

__device__ __forceinline__ short bf16_hi(float x) {
    return (short)(__float_as_uint(x) >> 16);  // truncation split
}
__device__ __forceinline__ float bf16_f(short s) {
    return __uint_as_float(((unsigned)(unsigned short)s) << 16);
}
// round-to-nearest-even fp32 -> bf16 bits
__device__ __forceinline__ unsigned short f2b_rne(float x) {
    unsigned u = __float_as_uint(x);
    u += 0x7fffu + ((u >> 16) & 1u);
    return (unsigned short)(u >> 16);
}

// split 8 consecutive fp32 (16B-aligned) into bf16 hi/lo fragments
__device__ __forceinline__ void split8(const float* p, short8& hi, short8& lo) {
    float4_ a = *(const float4_*)p;
    float4_ b = *(const float4_*)(p + 4);
    float v[8] = {a[0], a[1], a[2], a[3], b[0], b[1], b[2], b[3]};
    #pragma unroll
    for (int j = 0; j < 8; ++j) {
        short h = bf16_hi(v[j]);
        hi[j] = h;
        lo[j] = bf16_hi(v[j] - bf16_f(h));
    }
}

// load B-fragment (8 k-rows of one 16-col slice) from global weights, hi/lo split
__device__ __forceinline__ void load_b(const float* __restrict__ W, int ldw,
                                       int colbase, int krow, short8& hi, short8& lo) {
    #pragma unroll
    for (int j = 0; j < 8; ++j) {
        float wv = W[(krow + j) * ldw + colbase];
        short h = bf16_hi(wv);
        hi[j] = h;
        lo[j] = bf16_hi(wv - bf16_f(h));
    }
}

// fp32-accurate product via 3 bf16 MFMAs (drop lo*lo)
__device__ __forceinline__ float4_ mm3(short8 ah, short8 al, short8 bh, short8 bl,
                                       float4_ acc) {
    acc = __builtin_amdgcn_mfma_f32_16x16x32_bf16(ah, bh, acc, 0, 0, 0);
    acc = __builtin_amdgcn_mfma_f32_16x16x32_bf16(al, bh, acc, 0, 0, 0);
    acc = __builtin_amdgcn_mfma_f32_16x16x32_bf16(ah, bl, acc, 0, 0, 0);
    return acc;
}

// unpack 4 bf16 softmax weights from a dwordx2 and accumulate s, p*log2(p).
// Real p = exp(msg) >= 1.0; sentinel rows hold 1.0 (log2 = 0, s-count corrected
// analytically at finish) -> no fmax guard needed.
#define ACCQ(q, sv, nv) { \
    float p0_ = __uint_as_float((q).x << 16); \
    float p1_ = __uint_as_float((q).x & 0xffff0000u); \
    float p2_ = __uint_as_float((q).y << 16); \
    float p3_ = __uint_as_float((q).y & 0xffff0000u); \
    sv[0] += p0_; sv[1] += p1_; sv[2] += p2_; sv[3] += p3_; \
    nv[0] = fmaf(p0_, __log2f(p0_), nv[0]); \
    nv[1] = fmaf(p1_, __log2f(p1_), nv[1]); \
    nv[2] = fmaf(p2_, __log2f(p2_), nv[2]); \
    nv[3] = fmaf(p3_, __log2f(p3_), nv[3]); }

// ---------------- CSR build ----------------

__global__ void k_hist(const int* __restrict__ ei, int* __restrict__ cnt,
                       int* __restrict__ rank) {
    int e = blockIdx.x * blockDim.x + threadIdx.x;
    if (e < EE) rank[e] = atomicAdd(&cnt[ei[EE + e]], 1);
}

__global__ __launch_bounds__(1024) void k_scan1(const int* __restrict__ deg,
                                                int* __restrict__ excl,
                                                int* __restrict__ bsum) {
    __shared__ int ws[16];
    int tid = threadIdx.x, lane = tid & 63, w = tid >> 6;
    int gid = blockIdx.x * 1024 + tid;
    int v = (gid < NN) ? deg[gid] : 0;
    int x = v;
    #pragma unroll
    for (int d = 1; d < 64; d <<= 1) {
        int y = __shfl_up(x, d);
        if (lane >= d) x += y;
    }
    if (lane == 63) ws[w] = x;
    __syncthreads();
    if (tid == 0) {
        int acc = 0;
        for (int i = 0; i < 16; i++) { int t = ws[i]; ws[i] = acc; acc += t; }
        bsum[blockIdx.x] = acc;
    }
    __syncthreads();
    if (gid < NN) excl[gid] = x - v + ws[w];
}

// one-wave shuffle scan (nb <= 64)
__global__ void k_scan2(const int* __restrict__ bsum, int* __restrict__ boff, int nb) {
    int lane = threadIdx.x & 63;
    int v = (lane < nb) ? bsum[lane] : 0;
    int x = v;
    #pragma unroll
    for (int d = 1; d < 64; d <<= 1) {
        int y = __shfl_up(x, d);
        if (lane >= d) x += y;
    }
    if (lane < nb) boff[lane] = x - v;
}

__global__ __launch_bounds__(1024) void k_scan3(int* __restrict__ rp,
                                                const int* __restrict__ boff) {
    int gid = blockIdx.x * 1024 + threadIdx.x;
    if (gid < NN) rp[gid] += boff[blockIdx.x];
    if (gid == 0) rp[NN] = EE;
}

__global__ void k_scatter(const int* __restrict__ ei, const int* __restrict__ rp,
                          const int* __restrict__ rank, int* __restrict__ csrc) {
    int e = blockIdx.x * blockDim.x + threadIdx.x;
    if (e < EE) {
        int d = ei[EE + e];
        csrc[rp[d] + rank[e]] = ei[e];
    }
}

// ---------------- degree-bucket counting sort (DESCENDING: LPT scheduling) ----------------
// nd[pos] = {node, beg, deg, 0}; heavy nodes first so straggler blocks dispatch early.

__global__ __launch_bounds__(256) void k_dhist(const int* __restrict__ deg,
                                               int* __restrict__ bhist) {
    __shared__ int lh[64];
    int tid = threadIdx.x;
    if (tid < 64) lh[tid] = 0;
    __syncthreads();
    int n = blockIdx.x * 256 + tid;
    if (n < NN) atomicAdd(&lh[63 - min(deg[n], 63)], 1);
    __syncthreads();
    if (tid < 64 && lh[tid]) atomicAdd(&bhist[tid], lh[tid]);
}

__global__ void k_dscan(const int* __restrict__ bhist, int* __restrict__ gboff) {
    int lane = threadIdx.x & 63;
    int v = bhist[lane];
    int x = v;
    #pragma unroll
    for (int d = 1; d < 64; d <<= 1) {
        int y = __shfl_up(x, d);
        if (lane >= d) x += y;
    }
    gboff[lane] = x - v;
}

__global__ __launch_bounds__(256) void k_dscatter(const int* __restrict__ deg,
                                                  const int* __restrict__ rp,
                                                  int* __restrict__ gboff,
                                                  int4* __restrict__ nd) {
    __shared__ int lh[64], lbase[64];
    int tid = threadIdx.x;
    if (tid < 64) lh[tid] = 0;
    __syncthreads();
    int n = blockIdx.x * 256 + tid;
    int b = 0, lr = 0;
    if (n < NN) {
        b = 63 - min(deg[n], 63);
        lr = atomicAdd(&lh[b], 1);
    }
    __syncthreads();
    if (tid < 64) lbase[tid] = lh[tid] ? atomicAdd(&gboff[tid], lh[tid]) : 0;
    __syncthreads();
    if (n < NN) {
        int pos = lbase[b] + lr;
        nd[pos] = make_int4(n, rp[n], rp[n + 1] - rp[n], 0);
    }
}

// ---------------- Encoder: h0 = x @ enc_W + enc_b, plus P0 = bf16(exp(msg)) ----------------

__global__ __launch_bounds__(256) void k_enc(const float* __restrict__ x,
                                             const float* __restrict__ W,
                                             const float* __restrict__ b,
                                             float* __restrict__ h,
                                             unsigned short* __restrict__ P0,
                                             unsigned short* __restrict__ P1) {
    __shared__ float X[16 * 132];
    int tid = threadIdx.x, lane = tid & 63, w = tid >> 6;
    int nb = blockIdx.x * 16;
    int nq = lane >> 4, nr = lane & 15;
    int colbase = w * 16 + nr;

    // sentinel rows (index NN) = bf16 1.0 : log2 contributes 0, s corrected by count
    if (blockIdx.x == 0 && tid < HD) {
        P0[(size_t)NN * HD + tid] = 0x3f80;
        P1[(size_t)NN * HD + tid] = 0x3f80;
    }

    {
        const float* src = x + (size_t)nb * IND + tid * 8;
        float4_ a = *(const float4_*)src;
        float4_ c = *(const float4_*)(src + 4);
        int m = tid >> 4, k8 = 8 * (tid & 15);
        *(float4_*)&X[m * 132 + k8] = a;
        *(float4_*)&X[m * 132 + k8 + 4] = c;
    }
    __syncthreads();

    float4_ acc = {};
    #pragma unroll
    for (int t = 0; t < 4; ++t) {
        short8 ah, al, bh, bl;
        split8(&X[nr * 132 + t * 32 + nq * 8], ah, al);
        load_b(W, HD, colbase, t * 32 + nq * 8, bh, bl);
        acc = mm3(ah, al, bh, bl, acc);
    }

    float bias = b[colbase];
    #pragma unroll
    for (int r = 0; r < 4; ++r) {
        int node = nb + nq * 4 + r;
        float y = acc[r] + bias;
        h[node * HD + colbase] = y;
        float msg = fminf(fmaxf(y, 0.f) + 1e-7f, 50.f);
        P0[node * HD + colbase] = f2b_rne(__expf(msg));
    }
}

// ---------------- GENConv layer ----------------
// gather tail for rare deg > 64 nodes (correctness path)
__device__ __forceinline__ void gtail(const unsigned* __restrict__ Pb,
                                      const int* __restrict__ csrc,
                                      int beg, int deg, int g, int co, int lane,
                                      float4_& sv, float4_& nv, int& waste) {
    for (int chunk = 64; chunk < deg; chunk += 64) {
        int my = (chunk + lane < deg) ? csrc[beg + chunk + lane] : NN;
        int cnt = min(64, deg - chunk);
        int nb4 = (cnt + 3) >> 2;
        waste += nb4 * 4 - cnt;
        for (int k = 0; k < nb4; ++k) {
            int e = __shfl(my, k * 4 + g);
            uint2 q = *(const uint2*)(Pb + (((unsigned)e) << 5) + co);
            ACCQ(q, sv, nv);
        }
    }
}

// cross-group reduce + per-node epilogue (agg -> T row)
__device__ __forceinline__ void finish_node(float4_ sv, float4_ nv, int waste,
                                            int pnode, int row, int g, int ci,
                                            const float* __restrict__ selfh,
                                            uint2 selfq, float* __restrict__ T) {
    float t0 = sv[0], t1 = sv[1], t2 = sv[2], t3 = sv[3];
    float u0 = nv[0], u1 = nv[1], u2 = nv[2], u3 = nv[3];
    #pragma unroll
    for (int d = 16; d < 64; d <<= 1) {
        t0 += __shfl_xor(t0, d); t1 += __shfl_xor(t1, d);
        t2 += __shfl_xor(t2, d); t3 += __shfl_xor(t3, d);
        u0 += __shfl_xor(u0, d); u1 += __shfl_xor(u1, d);
        u2 += __shfl_xor(u2, d); u3 += __shfl_xor(u3, d);
    }
    if (g == 0) {
        float wf = (float)waste;   // each sentinel slot added exactly 1.0 to s
        float a0 = LN2 * u0 / fmaxf(t0 - wf, 1e-16f);
        float a1 = LN2 * u1 / fmaxf(t1 - wf, 1e-16f);
        float a2 = LN2 * u2 / fmaxf(t2 - wf, 1e-16f);
        float a3 = LN2 * u3 / fmaxf(t3 - wf, 1e-16f);
        float4_ xv;
        if (selfh) {
            float4_ sf = *(const float4_*)&selfh[(size_t)pnode * HD + ci * 4];
            xv[0] = sf[0] + a0; xv[1] = sf[1] + a1;
            xv[2] = sf[2] + a2; xv[3] = sf[3] + a3;
        } else {
            unsigned d0 = selfq.x, d1 = selfq.y;
            xv[0] = LN2 * __log2f(__uint_as_float(d0 << 16)) - 1e-7f + a0;
            xv[1] = LN2 * __log2f(__uint_as_float(d0 & 0xffff0000u)) - 1e-7f + a1;
            xv[2] = LN2 * __log2f(__uint_as_float(d1 << 16)) - 1e-7f + a2;
            xv[3] = LN2 * __log2f(__uint_as_float(d1 & 0xffff0000u)) - 1e-7f + a3;
        }
        *(float4_*)&T[row * 68 + ci * 4] = xv;
    }
}

__global__ __launch_bounds__(256, 4) void k_layer(const unsigned short* __restrict__ Pin,
                                                  const float* __restrict__ selfh,  // layer0 only
                                                  const float* __restrict__ hres,
                                                  float* __restrict__ hout,
                                                  unsigned short* __restrict__ Pout,
                                                  const int4* __restrict__ nd,
                                                  const int* __restrict__ csrc,
                                                  const float* __restrict__ W,
                                                  const float* __restrict__ b,
                                                  const float* __restrict__ gnext,
                                                  const float* __restrict__ bnext) {
    __shared__ float T[16 * 68];
    __shared__ int PN[16];
    int tid = threadIdx.x, lane = tid & 63, w = tid >> 6;
    int nb = blockIdx.x * 16;
    int nq = lane >> 4, nr = lane & 15;
    int colbase = w * 16 + nr;

    if (tid < 16) PN[tid] = nd[nb + tid].x;

    // B fragments, register-resident (issued before the gather loop)
    short8 Bhi[2], Blo[2];
    #pragma unroll
    for (int t = 0; t < 2; ++t)
        load_b(W, HD, colbase, t * 32 + nq * 8, Bhi[t], Blo[t]);

    int g = lane >> 4;
    int ci = lane & 15;
    int co = ci << 1;                     // dword offset within a P row
    const unsigned* Pb = (const unsigned*)Pin;

    // node descriptors (degree-sorted): {node, beg, deg}
    int4 dsc0 = nd[nb + w * 4 + 0];
    int4 dsc1 = nd[nb + w * 4 + 1];
    int4 dsc2 = nd[nb + w * 4 + 2];
    int4 dsc3 = nd[nb + w * 4 + 3];
    int p0n = dsc0.x, r0 = dsc0.y, dA = dsc0.z;
    int p1n = dsc1.x, r1 = dsc1.y, dB = dsc1.z;
    int p2n = dsc2.x, r2 = dsc2.y, dC = dsc2.z;
    int p3n = dsc3.x, r3 = dsc3.y, dD = dsc3.z;

    // first-chunk csrc preload for all 4 nodes; OOB lanes -> sentinel row NN
    int myA = (lane < dA) ? csrc[r0 + lane] : NN;
    int myB = (lane < dB) ? csrc[r1 + lane] : NN;
    int myC = (lane < dC) ? csrc[r2 + lane] : NN;
    int myD = (lane < dD) ? csrc[r3 + lane] : NN;

    // self-P preload (non-layer0 path); issued up-front to hide latency
    uint2 sq0 = {0, 0}, sq1 = {0, 0}, sq2 = {0, 0}, sq3 = {0, 0};
    if (!selfh) {
        sq0 = *(const uint2*)(Pb + (((unsigned)p0n) << 5) + co);
        sq1 = *(const uint2*)(Pb + (((unsigned)p1n) << 5) + co);
        sq2 = *(const uint2*)(Pb + (((unsigned)p2n) << 5) + co);
        sq3 = *(const uint2*)(Pb + (((unsigned)p3n) << 5) + co);
    }

    int cA = min(dA, 64), cB = min(dB, 64), cC = min(dC, 64), cD = min(dD, 64);
    int nk = (max(max(cA, cB), max(cC, cD)) + 3) >> 2;
    int wA = nk * 4 - cA, wB = nk * 4 - cB, wC = nk * 4 - cC, wD = nk * 4 - cD;

    float4_ sA = {}, nA = {}, sB = {}, nB = {}, sC = {}, nC = {}, sD = {}, nD = {};

    // interleaved gather: 4 independent bpermute->load chains per iteration;
    // exhausted nodes read the 1.0 sentinel row (counted, corrected at finish).
    #pragma unroll 2
    for (int k = 0; k < nk; ++k) {
        int sidx = k * 4 + g;
        int e0 = __shfl(myA, sidx);
        int e1 = __shfl(myB, sidx);
        int e2 = __shfl(myC, sidx);
        int e3 = __shfl(myD, sidx);
        uint2 q0 = *(const uint2*)(Pb + (((unsigned)e0) << 5) + co);
        uint2 q1 = *(const uint2*)(Pb + (((unsigned)e1) << 5) + co);
        uint2 q2 = *(const uint2*)(Pb + (((unsigned)e2) << 5) + co);
        uint2 q3 = *(const uint2*)(Pb + (((unsigned)e3) << 5) + co);
        ACCQ(q0, sA, nA);
        ACCQ(q1, sB, nB);
        ACCQ(q2, sC, nC);
        ACCQ(q3, sD, nD);
    }
    // rare deg>64 tails
    if (dA > 64) gtail(Pb, csrc, r0, dA, g, co, lane, sA, nA, wA);
    if (dB > 64) gtail(Pb, csrc, r1, dB, g, co, lane, sB, nB, wB);
    if (dC > 64) gtail(Pb, csrc, r2, dC, g, co, lane, sC, nC, wC);
    if (dD > 64) gtail(Pb, csrc, r3, dD, g, co, lane, sD, nD, wD);

    finish_node(sA, nA, wA, p0n, w * 4 + 0, g, ci, selfh, sq0, T);
    finish_node(sB, nB, wB, p1n, w * 4 + 1, g, ci, selfh, sq1, T);
    finish_node(sC, nC, wC, p2n, w * 4 + 2, g, ci, selfh, sq2, T);
    finish_node(sD, nD, wD, p3n, w * 4 + 3, g, ci, selfh, sq3, T);
    __syncthreads();

    short8 Ahi[2], Alo[2];
    #pragma unroll
    for (int t = 0; t < 2; ++t)
        split8(&T[nr * 68 + t * 32 + nq * 8], Ahi[t], Alo[t]);
    __syncthreads();  // all A reads done before T is overwritten

    float4_ acc = {};
    #pragma unroll
    for (int t = 0; t < 2; ++t)
        acc = mm3(Ahi[t], Alo[t], Bhi[t], Blo[t], acc);

    float bias = b[colbase];
    #pragma unroll
    for (int r = 0; r < 4; ++r) {
        int m = nq * 4 + r;
        int pn = PN[m];
        float v = acc[r] + bias;
        if (hres) v += hres[pn * HD + colbase];
        hout[pn * HD + colbase] = v;
        T[m * 68 + colbase] = v;
    }
    if (!Pout) return;
    __syncthreads();

    // LN phase: thread -> node tid>>4, 4 channels; emit P = bf16(exp(msg))
    int m = tid >> 4, c4 = (tid & 15) * 4;
    float4_ vv = *(const float4_*)&T[m * 68 + c4];
    float ps_ = (vv[0] + vv[1]) + (vv[2] + vv[3]);
    float pq_ = (vv[0] * vv[0] + vv[1] * vv[1]) + (vv[2] * vv[2] + vv[3] * vv[3]);
    #pragma unroll
    for (int d = 8; d; d >>= 1) {
        ps_ += __shfl_xor(ps_, d);
        pq_ += __shfl_xor(pq_, d);
    }
    float mu = ps_ * (1.f / 64.f);
    float var = pq_ * (1.f / 64.f) - mu * mu;
    float inv = rsqrtf(fmaxf(var, 0.f) + 1e-5f);
    float4_ g4 = *(const float4_*)&gnext[c4];
    float4_ b4 = *(const float4_*)&bnext[c4];
    ushort4_ po;
    #pragma unroll
    for (int j = 0; j < 4; ++j) {
        float y = fmaxf((vv[j] - mu) * inv * g4[j] + b4[j], 0.f);
        float msg = fminf(y + 1e-7f, 50.f);
        po[j] = f2b_rne(__expf(msg));
    }
    *(ushort4_*)&Pout[(size_t)PN[m] * HD + c4] = po;
}

// ---------------- Predictor: out = h @ pred_W + pred_b  (MFMA) ----------------

__global__ __launch_bounds__(256) void k_pred(const float* __restrict__ h,
                                              const float* __restrict__ W,
                                              const float* __restrict__ b,
                                              float* __restrict__ out) {
    __shared__ float T[16 * 68];
    int tid = threadIdx.x, lane = tid & 63, w = tid >> 6;
    int nb = blockIdx.x * 16;
    int nq = lane >> 4, nr = lane & 15;

    {
        const float* src = h + (size_t)nb * HD + tid * 4;
        float4_ a = *(const float4_*)src;
        int m = tid >> 4, k4 = 4 * (tid & 15);
        *(float4_*)&T[m * 68 + k4] = a;
    }
    __syncthreads();

    short8 Ahi[2], Alo[2];
    #pragma unroll
    for (int t = 0; t < 2; ++t)
        split8(&T[nr * 68 + t * 32 + nq * 8], Ahi[t], Alo[t]);

    for (int tt = w; tt < 7; tt += 4) {
        int colbase = tt * 16 + nr;
        float4_ acc = {};
        #pragma unroll
        for (int t = 0; t < 2; ++t) {
            short8 bh, bl;
            load_b(W, OUTD, colbase, t * 32 + nq * 8, bh, bl);
            acc = mm3(Ahi[t], Alo[t], bh, bl, acc);
        }
        float bias = b[colbase];
        #pragma unroll
        for (int r = 0; r < 4; ++r) {
            int node = nb + nq * 4 + r;
            out[node * OUTD + colbase] = acc[r] + bias;
        }
    }
}

// ---------------- Launch ----------------

extern "C" void kernel_launch(void* const* d_in, const int* in_sizes, int n_in,
                              void* d_out, int out_size, void* d_ws, size_t ws_size,
                              hipStream_t stream) {
    const float* x    = (const float*)d_in[0];
    const int*   ei   = (const int*)d_in[1];
    const float* encW = (const float*)d_in[2];
    const float* encb = (const float*)d_in[3];
    const float* lng  = (const float*)d_in[4];
    const float* lnb  = (const float*)d_in[5];
    const float* mlpW = (const float*)d_in[6];
    const float* mlpb = (const float*)d_in[7];
    const float* pW   = (const float*)d_in[8];
    const float* pb   = (const float*)d_in[9];
    float* out = (float*)d_out;

    int4* nd = (int4*)d_ws;                       // degree-sorted node descriptors
    float* hA  = (float*)(nd + NN);
    float* hB  = hA + (size_t)NN * HD;
    unsigned short* PA = (unsigned short*)(hB + (size_t)NN * HD);
    unsigned short* PB = PA + (size_t)(NN + 1) * HD;   // +1 row: sentinel
    int* rp    = (int*)(PB + (size_t)(NN + 1) * HD);
    int* cnt   = rp + (NN + 1);
    int* csrc  = cnt + NN;
    int* rank  = csrc + EE;
    int* bsum  = rank + EE;
    int* boff  = bsum + 64;
    int* bhist = boff + 64;
    int* gboff = bhist + 64;

    // CSR build (per call; ws is re-poisoned each launch)
    hipMemsetAsync(cnt, 0, NN * sizeof(int), stream);
    hipMemsetAsync(bhist, 0, 64 * sizeof(int), stream);
    k_hist<<<(EE + 255) / 256, 256, 0, stream>>>(ei, cnt, rank);
    const int NB = (NN + 1023) / 1024;  // 49
    k_scan1<<<NB, 1024, 0, stream>>>(cnt, rp, bsum);
    k_scan2<<<1, 64, 0, stream>>>(bsum, boff, NB);
    k_scan3<<<NB, 1024, 0, stream>>>(rp, boff);
    k_scatter<<<(EE + 255) / 256, 256, 0, stream>>>(ei, rp, rank, csrc);

    // degree-bucket sort (descending) -> nd
    const int NDB = (NN + 255) / 256;  // 196
    k_dhist<<<NDB, 256, 0, stream>>>(cnt, bhist);
    k_dscan<<<1, 64, 0, stream>>>(bhist, gboff);
    k_dscatter<<<NDB, 256, 0, stream>>>(cnt, rp, gboff, nd);

    // Encoder -> h_0 in hA, P_0 in PA (also writes both sentinel rows = 1.0)
    k_enc<<<NN / 16, 256, 0, stream>>>(x, encW, encb, hA, PA, PB);

    // Layer 0: self term = raw h0; writes h_1 -> hB, P_1 -> PB
    k_layer<<<NN / 16, 256, 0, stream>>>(PA, hA, nullptr, hB, PB, nd, csrc,
                                         mlpW, mlpb, lng, lnb);

    float* hres = hB;   // h_1
    float* hdst = hA;
    unsigned short* pc = PB;
    unsigned short* pn = PA;
    for (int l = 1; l < LL; ++l) {
        bool last = (l == LL - 1);
        k_layer<<<NN / 16, 256, 0, stream>>>(pc, nullptr, hres, hdst,
                                             last ? nullptr : pn,
                                             nd, csrc,
                                             mlpW + (size_t)l * HD * HD,
                                             mlpb + (size_t)l * HD,
                                             last ? nullptr : lng + (size_t)l * HD,
                                             last ? nullptr : lnb + (size_t)l * HD);
        float* t = hres; hres = hdst; hdst = t;
        unsigned short* u = pc; pc = pn; pn = u;
    }

    // Predictor on h_14
    k_pred<<<NN / 16, 256, 0, stream>>>(hres, pW, pb, out);
}